// Round 9
// baseline (356.708 us; speedup 1.0000x reference)
//
#include <hip/hip_runtime.h>
#include <cfloat>

// Problem constants
#define T_TOTAL 32768   // 32*32*32 spatial positions
#define DIM 64          // embedding dim
#define KCODES 1024     // num embeddings

// d_out flat layout (fp32 elements), reference return order:
//   quantized_out [32,64,32,32] = 2097152
//   loss (1), perplexity (1)
//   encodings [32768,1024] = 33554432
//   distances [32768,1024] = 33554432
static constexpr long long OFF_Q    = 0;
static constexpr long long OFF_LOSS = 2097152;
static constexpr long long OFF_PERP = 2097153;
static constexpr long long OFF_ENC  = 2097154;            // float idx % 4 == 2 -> region 8B aligned; enc+2 is 16B aligned
static constexpr long long OFF_DIST = 2097154LL + 33554432LL; // same alignment situation

// ws layout: [0,4096) int counts[1024]; [4096,8192) float ww[1024];
//            [8192,8196) float lossSum; [12288, 12288+256K) float WT[64][1024]

#define AS1 __attribute__((address_space(1)))
#define AS3 __attribute__((address_space(3)))

typedef float __attribute__((ext_vector_type(2))) f32x2;
typedef float __attribute__((ext_vector_type(4))) f32x4;

// Non-temporal streaming stores for the 256 MB of one-touch enc/dist/Q writes.
__device__ __forceinline__ void ntstore2(float* p, float a, float b) {
    f32x2 v = {a, b};
    __builtin_nontemporal_store(v, (f32x2*)p);
}
__device__ __forceinline__ void ntstore4z(float* p) {
    f32x4 v = {0.f, 0.f, 0.f, 0.f};
    __builtin_nontemporal_store(v, (f32x4*)p);
}
__device__ __forceinline__ void ntstore4(float* p, float a, float b, float c, float d) {
    f32x4 v = {a, b, c, d};
    __builtin_nontemporal_store(v, (f32x4*)p);
}

// Direct global->LDS DMA, 16B per lane. LDS dest must be wave-uniform base;
// HW writes lane i's 16B at base + i*16. Global src is per-lane.
__device__ __forceinline__ void gld16(const float* g, float* l) {
    __builtin_amdgcn_global_load_lds((const AS1 unsigned int*)g,
                                     (AS3 unsigned int*)l, 16, 0, 0);
}

// ---------------------------------------------------------------------------
// Prep: ||w_k||^2 (blocks 0..255) + W transpose WT[n][k] (blocks 256..319)
//     + enc row-boundary zero patches (blocks 320..383)
//     + counts/lossSum zeroing (block 384).
__global__ __launch_bounds__(256) void vq_prep_kernel(const float* __restrict__ W,
                                                      float* __restrict__ ww,
                                                      float* __restrict__ WT,
                                                      float* __restrict__ out,
                                                      int* __restrict__ counts,
                                                      float* __restrict__ lossSum) {
    const int tid = threadIdx.x;
    const int b   = blockIdx.x;
    if (b < 256) {
        const int lane = tid & 63;
        const int code = b * 4 + (tid >> 6);
        float v = W[code * DIM + lane];
        float s = v * v;
        #pragma unroll
        for (int off = 32; off > 0; off >>= 1)
            s += __shfl_down(s, off, 64);
        if (lane == 0) ww[code] = s;
    } else if (b < 320) {
        const int n = b - 256;            // 0..63
        #pragma unroll
        for (int i = 0; i < 4; ++i) {
            int k = i * 256 + tid;
            WT[n * KCODES + k] = W[k * DIM + n];
        }
    } else if (b < 384) {
        // enc boundary patches: floats {0,1} and {1022,1023} of every row
        // (main's streaming covers the 16B-aligned interior [2,1022)).
        float* __restrict__ enc = out + OFF_ENC;
        const int r0 = (b - 320) * 512 + tid * 2;   // 2 rows per thread
        const long long rb = (long long)r0 * KCODES;
        ntstore2(&enc[rb], 0.f, 0.f);
        ntstore2(&enc[rb + 1022], 0.f, 0.f);
        ntstore2(&enc[rb + 1024], 0.f, 0.f);
        ntstore2(&enc[rb + 1024 + 1022], 0.f, 0.f);
    } else {
        #pragma unroll
        for (int i = 0; i < 4; ++i) counts[i * 256 + tid] = 0;
        if (tid == 0) lossSum[0] = 0.f;
    }
}

// ---------------------------------------------------------------------------
// Main fused kernel — BARRIER-FREE K-LOOP STRUCTURE (R8 post-mortem: vmcnt is
// an in-order per-wave FIFO, so ANY per-phase counted wait transitively drains
// all older stores; every prior schedule paid a full store-drain per phase).
// 512 blocks x 512 threads (8 waves); each block owns 64 rows.
// LDS: whole 512-code W-chunk resident (128 KB) + xT (16 KB) + wwS (4 KB)
//   = 148.5 KB -> 1 block/CU. Per chunk: K-loop over all 64 dims with ZERO
//   barriers / ZERO vmcnt waits (only compiler lgkmcnt). Stores (enc zeros,
//   dist) free-flow across ~30us of compute. Exactly ONE counted wait per
//   kernel (chunk boundary, vmcnt(32) retires only the 16 re-stage loads;
//   issue order loads->enc->dist makes the count robust to store merging)
//   and ONE full drain (epilogue __syncthreads before enc 1.0 fixups).
// Thread tiling: wave ty owns rows ty*8..+7 (a-reads wave-uniform broadcast);
// lane tx owns codes {g*256 + tx*4 + j}; acc[8][8]. Per-row argmin is
// wave-internal -> 6-step shuffle butterfly.
__global__ __launch_bounds__(512, 1) void vq_main_kernel(const float* __restrict__ lat,
                                                         const float* __restrict__ W,
                                                         const float* __restrict__ ww,
                                                         const float* __restrict__ WT,
                                                         float* __restrict__ out,
                                                         int* __restrict__ counts,
                                                         float* __restrict__ lossSum) {
    __shared__ float xT[64 * 64];      // [n][tl] 16 KB — persistent
    __shared__ float wC[64 * 512];     // [n][k] 128 KB — one full code-chunk; reused for qS
    __shared__ float wwS[KCODES];      // ||w||^2, 4 KB
    __shared__ float xx[64];           // ||x_row||^2
    __shared__ int   selIdx[64];

    const int tid = threadIdx.x;       // 0..511
    const int tx  = tid & 63;          // lane
    const int ty  = tid >> 6;          // wave 0..7 = row-group
    const int t0  = blockIdx.x * 64;
    // flat row t maps to latent addr b*65536 + n*1024 + (j*32+d); for a 64-row
    // block the (j*32+d) part is contiguous: base + n*1024 + tl
    const long long base = (long long)(t0 >> 10) * 65536 + (long long)(t0 & 1023);
    const int wbase = (tid & 448) * 4; // wave-uniform float-offset component of LDS dest

    // ---- prologue: DMA x tile (16 KB) + chunk-0 W panel (128 KB) into LDS
    #pragma unroll
    for (int i = 0; i < 2; ++i) {
        const int e = i * 512 + tid;   // f4 index in [0,1024): n = e>>4, tl4 = e&15
        gld16(&lat[base + (long long)(e >> 4) * 1024 + (e & 15) * 4],
              &xT[i * 2048 + wbase]);
    }
    #pragma unroll
    for (int i = 0; i < 16; ++i) {
        const int e = i * 512 + tid;   // f4 index in [0,8192): n = e>>7, k4 = e&127
        gld16(&WT[(e >> 7) * KCODES + (e & 127) * 4],
              &wC[i * 2048 + wbase]);
    }
    *(float2*)&wwS[tid * 2] = *(const float2*)&ww[tid * 2];
    __syncthreads();                   // full drain (no stores yet) — cheap

    // ||x||^2 per row (wave 0; published by the chunk-0 boundary barrier,
    // first consumed in chunk-0's dist section after that barrier)
    if (tid < 64) {
        float s = 0.f;
        #pragma unroll 8
        for (int n = 0; n < 64; ++n) {
            float v = xT[n * 64 + tid];
            s = fmaf(v, v, s);
        }
        xx[tid] = s;
    }

    float minV[8];
    int   minI[8];
    #pragma unroll
    for (int r = 0; r < 8; ++r) { minV[r] = FLT_MAX; minI[r] = 0; }

    float acc[8][8];
    float* __restrict__ distOut = out + OFF_DIST;
    float* __restrict__ enc     = out + OFF_ENC;

    #pragma unroll 1
    for (int c = 0; c < 2; ++c) {
        #pragma unroll
        for (int r = 0; r < 8; ++r)
            #pragma unroll
            for (int k = 0; k < 8; ++k) acc[r][k] = 0.f;

        // ---- K-loop: all 64 dims, NO barriers, NO vmcnt waits.
        // a-reads: wave-uniform b128 broadcasts (rows ty*8..+7).
        // b-reads: 2x b128, contiguous per 16-lane beat -> conflict-free.
        #pragma unroll 4
        for (int n = 0; n < 64; ++n) {
            const float* xrow = &xT[n * 64 + ty * 8];
            const float* wrow = &wC[n * 512];
            float4 a0 = *(const float4*)&xrow[0];
            float4 a1 = *(const float4*)&xrow[4];
            float4 b0 = *(const float4*)&wrow[tx * 4];
            float4 b1 = *(const float4*)&wrow[256 + tx * 4];
            float ar[8] = {a0.x, a0.y, a0.z, a0.w, a1.x, a1.y, a1.z, a1.w};
            float br[8] = {b0.x, b0.y, b0.z, b0.w, b1.x, b1.y, b1.z, b1.w};
            #pragma unroll
            for (int r = 0; r < 8; ++r)
                #pragma unroll
                for (int k = 0; k < 8; ++k)
                    acc[r][k] = fmaf(ar[r], br[k], acc[r][k]);
        }

        // ---- chunk boundary: all wC reads done (per-wave lgkm drain, then
        // barrier WITHOUT vmcnt drain — raw s_barrier, not __syncthreads).
        asm volatile("s_waitcnt lgkmcnt(0)" ::: "memory");
        __builtin_amdgcn_s_barrier();
        __builtin_amdgcn_sched_barrier(0);

        // (1) re-stage wC with chunk 1's panel — issued FIRST (oldest VMEM).
        if (c == 0) {
            #pragma unroll
            for (int i = 0; i < 16; ++i) {
                const int e = i * 512 + tid;
                gld16(&WT[(e >> 7) * KCODES + 512 + (e & 127) * 4],
                      &wC[i * 2048 + wbase]);
            }
        }
        asm volatile("" ::: "memory");

        // (2) enc zero-fill for this chunk's 32 rows (16 nt f4/thread,
        // non-adjacent -> never merged; boundaries {0,1,1022,1023} from prep)
        {
            float* encBase = enc + (long long)(t0 + c * 32) * KCODES + 2;
            #pragma unroll
            for (int i = 0; i < 16; ++i) {
                const int e   = i * 512 + tid;   // [0,8192) = 32 rows x 256 slots
                const int row = e >> 8;
                const int j   = e & 255;
                const int jc  = j > 254 ? 254 : j;   // clamp dup (benign)
                ntstore4z(encBase + (long long)row * KCODES + jc * 4);
            }
        }
        asm volatile("" ::: "memory");

        // (3) distances out (nt) + running argmin for this chunk.
        // thread's codes: k = c*512 + g*256 + tx*4 + j — ascending scan order,
        // strict < keeps the first (np.argmin tie semantics)
        {
            const int kbl = tx * 4;
            float wr[8];
            float4 wa = *(const float4*)&wwS[c * 512 + kbl];
            float4 wb = *(const float4*)&wwS[c * 512 + 256 + kbl];
            wr[0]=wa.x; wr[1]=wa.y; wr[2]=wa.z; wr[3]=wa.w;
            wr[4]=wb.x; wr[5]=wb.y; wr[6]=wb.z; wr[7]=wb.w;
            #pragma unroll
            for (int r = 0; r < 8; ++r) {
                const int row = ty * 8 + r;
                const float xxr = xx[row];           // wave-uniform
                const long long ro = (long long)(t0 + row) * KCODES + c * 512 + kbl;
                #pragma unroll
                for (int g = 0; g < 2; ++g) {
                    float d0 = (xxr + wr[g*4+0]) - 2.f * acc[r][g*4+0];
                    float d1 = (xxr + wr[g*4+1]) - 2.f * acc[r][g*4+1];
                    float d2 = (xxr + wr[g*4+2]) - 2.f * acc[r][g*4+2];
                    float d3 = (xxr + wr[g*4+3]) - 2.f * acc[r][g*4+3];
                    const int k0 = c * 512 + g * 256 + kbl;
                    if (d0 < minV[r]) { minV[r] = d0; minI[r] = k0;     }
                    if (d1 < minV[r]) { minV[r] = d1; minI[r] = k0 + 1; }
                    if (d2 < minV[r]) { minV[r] = d2; minI[r] = k0 + 2; }
                    if (d3 < minV[r]) { minV[r] = d3; minI[r] = k0 + 3; }
                    ntstore2(&distOut[ro + g * 256],     d0, d1);
                    ntstore2(&distOut[ro + g * 256 + 2], d2, d3);
                }
            }
        }

        // (4) the kernel's ONLY in-loop counted wait: outstanding =
        // [16 loads (oldest), 16 enc, >=16 dist]. vmcnt(32) keeps the 32
        // newest (stores only) -> retires all 16 loads + at most 16 stores,
        // robust to any store merging. Then barrier -> wC(c1) ready.
        if (c == 0) {
            asm volatile("s_waitcnt vmcnt(32)" ::: "memory");
            __builtin_amdgcn_s_barrier();
            __builtin_amdgcn_sched_barrier(0);
        }
    }

    // ---- per-row argmin: candidates for row ty*8+r live in this wave's 64
    // lanes -> 6-step butterfly on (val,idx); lane r publishes row r.
    #pragma unroll
    for (int r = 0; r < 8; ++r) {
        float v  = minV[r];
        int   bi = minI[r];
        #pragma unroll
        for (int off = 1; off < 64; off <<= 1) {
            float v2 = __shfl_xor(v, off, 64);
            int   i2 = __shfl_xor(bi, off, 64);
            if (v2 < v || (v2 == v && i2 < bi)) { v = v2; bi = i2; }
        }
        if (tx == r) {
            selIdx[ty * 8 + r] = bi;
            atomicAdd(&counts[bi], 1);
        }
    }
    __syncthreads();                   // FULL drain (once): retires all enc/dist
                                       // stores (required before enc 1.0 fixups);
                                       // publishes selIdx; wC free for reuse

    // ---- gather selected codebook rows into LDS (coalesced), stride 65 kills conflicts
    float* qS = wC;
    #pragma unroll
    for (int i = 0; i < 8; ++i) {
        int e   = i * 512 + tid;       // [0,4096)
        int row = e >> 6;
        int n   = e & 63;
        qS[row * 65 + n] = W[selIdx[row] * DIM + n];
    }
    __syncthreads();

    // ---- quantized_out (nt float4, 16B aligned) + loss partial
    float ls = 0.f;
    #pragma unroll
    for (int i = 0; i < 2; ++i) {
        int e2  = i * 512 + tid;       // [0,1024) float4s
        int n   = e2 >> 4;
        int tl0 = (e2 & 15) * 4;
        float q0 = qS[(tl0 + 0) * 65 + n];
        float q1 = qS[(tl0 + 1) * 65 + n];
        float q2 = qS[(tl0 + 2) * 65 + n];
        float q3 = qS[(tl0 + 3) * 65 + n];
        float x0 = xT[n * 64 + tl0 + 0];
        float x1 = xT[n * 64 + tl0 + 1];
        float x2 = xT[n * 64 + tl0 + 2];
        float x3 = xT[n * 64 + tl0 + 3];
        ntstore4(&out[OFF_Q + base + (long long)n * 1024 + tl0], q0, q1, q2, q3);
        float e0 = q0 - x0; ls = fmaf(e0, e0, ls);
        float e1 = q1 - x1; ls = fmaf(e1, e1, ls);
        float e2d = q2 - x2; ls = fmaf(e2d, e2d, ls);
        float e3 = q3 - x3; ls = fmaf(e3, e3, ls);
    }
    #pragma unroll
    for (int off = 32; off > 0; off >>= 1)
        ls += __shfl_down(ls, off, 64);
    if ((tid & 63) == 0) atomicAdd(lossSum, ls);

    // ---- one-hot fix-up: all zeros drained by the epilogue __syncthreads;
    // a single 1.0 store per row completes encodings.
    if (tid < 64)
        enc[(long long)(t0 + tid) * KCODES + selIdx[tid]] = 1.f;
}

// ---------------------------------------------------------------------------
// Finalize: perplexity from histogram, loss from accumulated SSE.
__global__ __launch_bounds__(1024) void vq_finalize_kernel(const int* __restrict__ counts,
                                                           const float* __restrict__ lossSum,
                                                           float* __restrict__ out) {
    __shared__ float red[16];
    const int tid = threadIdx.x;
    float p = (float)counts[tid] * (1.0f / 32768.0f);   // exact (pow2 divisor)
    float term = p * logf(p + 1e-10f);
    #pragma unroll
    for (int off = 32; off > 0; off >>= 1)
        term += __shfl_down(term, off, 64);
    if ((tid & 63) == 0) red[tid >> 6] = term;
    __syncthreads();
    if (tid == 0) {
        float s = 0.f;
        #pragma unroll
        for (int i = 0; i < 16; ++i) s += red[i];
        out[OFF_PERP] = expf(-s);
        out[OFF_LOSS] = 0.25f * lossSum[0] * (1.0f / 2097152.0f);  // COMMIT_COST * mean SSE
    }
}

// ---------------------------------------------------------------------------
extern "C" void kernel_launch(void* const* d_in, const int* in_sizes, int n_in,
                              void* d_out, int out_size, void* d_ws, size_t ws_size,
                              hipStream_t stream) {
    (void)in_sizes; (void)n_in; (void)out_size; (void)ws_size;
    const float* lat = (const float*)d_in[0];   // [32,64,32,32]
    const float* W   = (const float*)d_in[1];   // [1024,64]
    float* out = (float*)d_out;

    int*   counts  = (int*)d_ws;
    float* ww      = (float*)((char*)d_ws + 4096);
    float* lossSum = (float*)((char*)d_ws + 8192);
    float* WT      = (float*)((char*)d_ws + 12288);   // 64x1024 fp32 = 256 KB

    // prep zeroes counts/lossSum (block 384) — no hipMemsetAsync dispatch needed
    vq_prep_kernel<<<385, 256, 0, stream>>>(W, ww, WT, out, counts, lossSum);
    vq_main_kernel<<<512, 512, 0, stream>>>(lat, W, ww, WT, out, counts, lossSum);
    vq_finalize_kernel<<<1, 1024, 0, stream>>>(counts, lossSum, out);
}